// Round 5
// baseline (190.149 us; speedup 1.0000x reference)
//
#include <hip/hip_runtime.h>
#include <math.h>

#define PAD_ID 12975
#define BB 256
#define SS 200
#define DD 1024
#define HH 16

#define MASK_CHUNKS (BB * HH * SS * (SS / 4))   // 40,960,000 float4 chunks total
#define CHUNKS_PER_B (HH * SS * (SS / 4))       // 160,000 per batch row
#define BLKS_PER_B 5                            // 5 mask blocks per b
#define CHUNKS_PER_BLK (CHUNKS_PER_B / BLKS_PER_B)  // 32,000

#define OUT_ROWS (BB * SS)                      // 51,200 rows of 1024 floats

#define MBLK (BB * BLKS_PER_B)                  // 1280 mask blocks
#define OB   768                                // out blocks
#define NBLK (MBLK + OB)                        // 2048 == 8 blocks/CU, all resident

typedef float f32x4 __attribute__((ext_vector_type(4)));
typedef int   i32x4 __attribute__((ext_vector_type(4)));

// Single fused kernel, no prep launch.
//  blocks [0,1280):    mask. block m -> b = m/5, owns chunks [q*32000,(q+1)*32000)
//                      of b's 2.56MB region. Scans only x[b,:] (800B) into an LDS
//                      pad pattern + first_b; inner loop = LDS read + nt store.
//  blocks [1280,2048): out[row,:] = weight[x[row],:] + sinusoid(row%S,:).
//                      sin/cos via HW v_sin/v_cos on fract-reduced revolutions.
__global__ void __launch_bounds__(256) work_kernel(const int* __restrict__ x,
                                                   const float* __restrict__ weight,
                                                   float* __restrict__ out,
                                                   float* __restrict__ mask) {
    if (blockIdx.x < MBLK) {
        const int b = blockIdx.x / BLKS_PER_B;
        const int q = blockIdx.x - b * BLKS_PER_B;
        __shared__ f32x4 pat[SS / 4];   // pad-row pattern, 800B
        __shared__ int   sfirst;
        if (threadIdx.x == 0) sfirst = SS - 1;   // no-pad => S-1 (reference semantics)
        __syncthreads();
        if (threadIdx.x < SS / 4) {
            const i32x4 xv = ((const i32x4*)(x + b * SS))[threadIdx.x];
            f32x4 p;
            p.x = (xv.x == PAD_ID) ? 1.f : 0.f;
            p.y = (xv.y == PAD_ID) ? 1.f : 0.f;
            p.z = (xv.z == PAD_ID) ? 1.f : 0.f;
            p.w = (xv.w == PAD_ID) ? 1.f : 0.f;
            pat[threadIdx.x] = p;
            int f = 255;                          // min pad index among this lane's 4
            if (xv.w == PAD_ID) f = threadIdx.x * 4 + 3;
            if (xv.z == PAD_ID) f = threadIdx.x * 4 + 2;
            if (xv.y == PAD_ID) f = threadIdx.x * 4 + 1;
            if (xv.x == PAD_ID) f = threadIdx.x * 4 + 0;
            atomicMin(&sfirst, f);                // f=255 > init 199: harmless
        }
        __syncthreads();
        const int first = sfirst;
        const f32x4 ones = (f32x4){1.f, 1.f, 1.f, 1.f};
        f32x4* const mptr = (f32x4*)mask + (size_t)b * CHUNKS_PER_B;
        const int base = q * CHUNKS_PER_BLK;
        for (int c = threadIdx.x; c < CHUNKS_PER_BLK; c += 256) {
            const int d  = base + c;            // chunk within b's region
            const int r  = d / 50;              // (h*200 + i)
            const int j4 = d - r * 50;
            const int i  = r % SS;
            const f32x4 v = (i >= first) ? ones : pat[j4];
            __builtin_nontemporal_store(v, mptr + d);
        }
    } else {
        const int t = threadIdx.x;               // handles j = 4t..4t+3
        const float C = (float)(13.287712379549449 / 512.0);   // log2(10000)/512
        // rd = 1/10000^(p/512), p = 2t, 2t+1 — loop-invariant per thread
        const float rd0 = exp2f(-(float)(2 * t) * C);
        const float rd1 = exp2f(-(float)(2 * t + 1) * C);
        const float INV2PI = 0.15915493667125702f;
        for (int row = blockIdx.x - MBLK; row < OUT_ROWS; row += OB) {
            const int s   = row % SS;
            const int idx = x[row];              // block-uniform
            const float fs = (float)s;
            // angle -> revolutions -> fract -> HW sin/cos (v_sin needs reduced input)
            float r0 = fs * rd0 * INV2PI;  r0 -= floorf(r0);
            float r1 = fs * rd1 * INV2PI;  r1 -= floorf(r1);
            f32x4 pe;
            pe.x = __builtin_amdgcn_sinf(r0);
            pe.y = __builtin_amdgcn_cosf(r0);
            pe.z = __builtin_amdgcn_sinf(r1);
            pe.w = __builtin_amdgcn_cosf(r1);
            const f32x4 w = ((const f32x4*)(weight + (size_t)idx * DD))[t];
            __builtin_nontemporal_store(w + pe, (f32x4*)(out + (size_t)row * DD) + t);
        }
    }
}

extern "C" void kernel_launch(void* const* d_in, const int* in_sizes, int n_in,
                              void* d_out, int out_size, void* d_ws, size_t ws_size,
                              hipStream_t stream) {
    const int*   x      = (const int*)d_in[0];
    const float* weight = (const float*)d_in[1];
    float* out  = (float*)d_out;
    float* mask = out + (size_t)BB * SS * DD;   // outputs concatenated: (out, mask)

    work_kernel<<<NBLK, 256, 0, stream>>>(x, weight, out, mask);
}

// Round 6
// 178.866 us; speedup vs baseline: 1.0631x; 1.0631x over previous
//
#include <hip/hip_runtime.h>
#include <math.h>

#define PAD_ID 12975
#define BB 256
#define SS 200
#define DD 1024
#define HH 16

#define MASK_CHUNKS (BB * HH * SS * (SS / 4))   // 40,960,000 f32x4 units (mask)
#define OUT_ROWS    (BB * SS)                   // 51,200
#define OUT_CHUNKS  (OUT_ROWS * (DD / 4))       // 13,107,200 f32x4 units (out)
#define TOTAL_UNITS (MASK_CHUNKS + OUT_CHUNKS)  // 54,067,200

#define NBLK 2048      // 8 blocks/CU, all resident; unified grid-stride = auto-balance

typedef float f32x4 __attribute__((ext_vector_type(4)));
typedef int   i32x4 __attribute__((ext_vector_type(4)));

// ws layout: [0,1024): int first[256]; [1024, 1024+819200): float posT[200*1024]
#define WS_FIRST_BYTES 1024
#define WS_POST_BYTES  (SS * DD * 4)

// ---------- prep: sinusoid table + first-pad index (identical to R3) ----------
__global__ void prep_kernel(const int* __restrict__ x, int* __restrict__ first,
                            float* __restrict__ posT) {
    const int idx = blockIdx.x * blockDim.x + threadIdx.x;
    if (idx < SS * DD) {
        const int s = idx >> 10;           // /1024
        const int j = idx & (DD - 1);
        const int p = j >> 1;
        const float C = (float)(13.287712379549449 / 512.0);  // log2(10000)/512
        const float angle = (float)s / exp2f((float)p * C);
        posT[idx] = (j & 1) ? cosf(angle) : sinf(angle);
    }
    if (blockIdx.x < BB) {
        __shared__ int sfirst;
        if (threadIdx.x == 0) sfirst = SS - 1;   // no-pad => S-1 (reference semantics)
        __syncthreads();
        if (threadIdx.x < SS && x[blockIdx.x * SS + threadIdx.x] == PAD_ID)
            atomicMin(&sfirst, threadIdx.x);
        __syncthreads();
        if (threadIdx.x == 0) first[blockIdx.x] = sfirst;
    }
}

// ---------- work: unified unit space, grid-stride, auto-balanced ----------
// units [0, MASK_CHUNKS):              mask f32x4 chunks (R3's exact body)
// units [MASK_CHUNKS, TOTAL_UNITS):    out f32x4 chunks  (R3's exact body)
__global__ void work_kernel(const int* __restrict__ x, const int* __restrict__ first,
                            const float* __restrict__ weight, const float* __restrict__ posT,
                            float* __restrict__ out, float* __restrict__ mask) {
    const int stride = NBLK * 256;
    const f32x4 ones = (f32x4){1.f, 1.f, 1.f, 1.f};
    for (int u = blockIdx.x * 256 + threadIdx.x; u < TOTAL_UNITS; u += stride) {
        if (u < MASK_CHUNKS) {
            // mask[b,h,i,j] = (x[b,j]==PAD) || (i>=first[b]) ? 1 : 0
            const int row = u / 50;              // 50 f32x4 per S=200 row
            const int j4  = u - row * 50;
            const int b   = row / (HH * SS);     // /3200
            const int i   = row % SS;
            f32x4 v;
            if (i >= first[b]) {
                v = ones;
            } else {
                const i32x4 xv = ((const i32x4*)x)[b * 50 + j4];   // 204KB, L2-hot
                v.x = (xv.x == PAD_ID) ? 1.f : 0.f;
                v.y = (xv.y == PAD_ID) ? 1.f : 0.f;
                v.z = (xv.z == PAD_ID) ? 1.f : 0.f;
                v.w = (xv.w == PAD_ID) ? 1.f : 0.f;
            }
            __builtin_nontemporal_store(v, (f32x4*)mask + u);
        } else {
            // out[row, 4t..4t+3] = weight[x[row], ...] + posT[row%S, ...]
            const int o   = u - MASK_CHUNKS;
            const int row = o >> 8;              // 256 f32x4 per row
            const int t   = o & 255;
            const int s   = row % SS;
            const int idx = x[row];              // wave-uniform (same row per wave mostly)
            const f32x4 w  = ((const f32x4*)(weight + (size_t)idx * DD))[t];
            const f32x4 pe = ((const f32x4*)(posT + (size_t)s * DD))[t];
            __builtin_nontemporal_store(w + pe, (f32x4*)out + o);
        }
    }
}

extern "C" void kernel_launch(void* const* d_in, const int* in_sizes, int n_in,
                              void* d_out, int out_size, void* d_ws, size_t ws_size,
                              hipStream_t stream) {
    const int*   x      = (const int*)d_in[0];
    const float* weight = (const float*)d_in[1];
    float* out  = (float*)d_out;
    float* mask = out + (size_t)BB * SS * DD;   // outputs concatenated: (out, mask)

    int*   first = (int*)d_ws;
    float* posT  = (float*)((char*)d_ws + WS_FIRST_BYTES);

    prep_kernel<<<(SS * DD + 255) / 256, 256, 0, stream>>>(x, first, posT);
    work_kernel<<<NBLK, 256, 0, stream>>>(x, first, weight, posT, out, mask);
}

// Round 8
// 168.951 us; speedup vs baseline: 1.1255x; 1.0587x over previous
//
#include <hip/hip_runtime.h>
#include <math.h>

#define PAD_ID 12975
#define BB 256
#define SS 200
#define DD 1024
#define HH 16

#define MASK_CHUNKS (BB * HH * SS * (SS / 4))   // 40,960,000 f32x4 units (mask)
#define OUT_ROWS    (BB * SS)                   // 51,200
#define OUT_CHUNKS  (OUT_ROWS * (DD / 4))       // 13,107,200 f32x4 units (out)

// Wave-chunk spaces: 64 consecutive f32x4 per wave-chunk.
//   mask: 640,000 wave-chunks; out: 204,800. Ratio 25:8 EXACTLY, and 25/33
//   = 75.8% equals mask's share of write bytes (655MB/865MB). One unified
//   space of 844,800 wave-chunks, interleaved 25 mask : 8 out -> at every
//   instant ~76% of waves stream mask writes while ~24% gather weight rows:
//   reads overlap writes for the whole kernel, auto-balanced, no tail.
#define WU_TOTAL (844800)
#define NBLK 2048                               // 8192 waves = 8 blocks/CU resident
#define NWAVES (NBLK * 256 / 64)

typedef float f32x4 __attribute__((ext_vector_type(4)));
typedef int   i32x4 __attribute__((ext_vector_type(4)));

// ws layout: [0,1024): int first[256]; [1024, 1024+819200): float posT[200*1024]
#define WS_FIRST_BYTES 1024

// ---------- prep: sinusoid table + first-pad index (identical to R3) ----------
__global__ void prep_kernel(const int* __restrict__ x, int* __restrict__ first,
                            float* __restrict__ posT) {
    const int idx = blockIdx.x * blockDim.x + threadIdx.x;
    if (idx < SS * DD) {
        const int s = idx >> 10;           // /1024
        const int j = idx & (DD - 1);
        const int p = j >> 1;
        const float C = (float)(13.287712379549449 / 512.0);  // log2(10000)/512
        const float angle = (float)s / exp2f((float)p * C);
        posT[idx] = (j & 1) ? cosf(angle) : sinf(angle);
    }
    if (blockIdx.x < BB) {
        __shared__ int sfirst;
        if (threadIdx.x == 0) sfirst = SS - 1;   // no-pad => S-1 (reference semantics)
        __syncthreads();
        if (threadIdx.x < SS && x[blockIdx.x * SS + threadIdx.x] == PAD_ID)
            atomicMin(&sfirst, threadIdx.x);
        __syncthreads();
        if (threadIdx.x == 0) first[blockIdx.x] = sfirst;
    }
}

// ---------- work: wave-interleaved 25:8 mask/out, bodies identical to R3 ----------
__global__ void work_kernel(const int* __restrict__ x, const int* __restrict__ first,
                            const float* __restrict__ weight, const float* __restrict__ posT,
                            float* __restrict__ out, float* __restrict__ mask) {
    const int wave = (blockIdx.x * 256 + threadIdx.x) >> 6;   // global wave id
    const int lane = threadIdx.x & 63;
    const f32x4 ones = (f32x4){1.f, 1.f, 1.f, 1.f};
    for (int wu = wave; wu < WU_TOTAL; wu += NWAVES) {
        const int g = wu / 33;               // magic-mul
        const int r = wu - g * 33;
        if (r < 25) {
            // ---- mask wave-chunk: 64 consecutive f32x4 ----
            const int u  = (g * 25 + r) * 64 + lane;
            const int row = u / 50;              // 50 f32x4 per S=200 row
            const int j4  = u - row * 50;
            const int b   = row / (HH * SS);     // /3200
            const int i   = row % SS;
            f32x4 v;
            if (i >= first[b]) {
                v = ones;
            } else {
                const i32x4 xv = ((const i32x4*)x)[b * 50 + j4];   // 204KB, cache-hot
                v.x = (xv.x == PAD_ID) ? 1.f : 0.f;
                v.y = (xv.y == PAD_ID) ? 1.f : 0.f;
                v.z = (xv.z == PAD_ID) ? 1.f : 0.f;
                v.w = (xv.w == PAD_ID) ? 1.f : 0.f;
            }
            __builtin_nontemporal_store(v, (f32x4*)mask + u);
        } else {
            // ---- out wave-chunk: 64 consecutive f32x4, wave-uniform row ----
            const int o   = (g * 8 + (r - 25)) * 64 + lane;
            const int row = o >> 8;              // uniform across the wave
            const int t   = o & 255;
            const int s   = row % SS;
            const int idx = x[row];              // wave-uniform scalar load
            const f32x4 w  = ((const f32x4*)(weight + (size_t)idx * DD))[t];
            const f32x4 pe = ((const f32x4*)(posT + (size_t)s * DD))[t];
            __builtin_nontemporal_store(w + pe, (f32x4*)out + o);
        }
    }
}

extern "C" void kernel_launch(void* const* d_in, const int* in_sizes, int n_in,
                              void* d_out, int out_size, void* d_ws, size_t ws_size,
                              hipStream_t stream) {
    const int*   x      = (const int*)d_in[0];
    const float* weight = (const float*)d_in[1];
    float* out  = (float*)d_out;
    float* mask = out + (size_t)BB * SS * DD;   // outputs concatenated: (out, mask)

    int*   first = (int*)d_ws;
    float* posT  = (float*)((char*)d_ws + WS_FIRST_BYTES);

    prep_kernel<<<(SS * DD + 255) / 256, 256, 0, stream>>>(x, first, posT);
    work_kernel<<<NBLK, 256, 0, stream>>>(x, first, weight, posT, out, mask);
}

// Round 9
// 165.063 us; speedup vs baseline: 1.1520x; 1.0236x over previous
//
#include <hip/hip_runtime.h>
#include <math.h>

#define PAD_ID 12975
#define BB 256
#define SS 200
#define DD 1024
#define HH 16

#define MASK_CHUNKS (BB * HH * SS * (SS / 4))   // 40,960,000 float4 chunks
#define OUT_ROWS    (BB * SS)                   // 51,200 rows of 1024 floats

#define NBLK 2048      // total blocks (8/CU, all resident; BW reallocates dynamically)
#define MBLK 1376      // mask partition vs out partition — R3's empirically-best split

typedef float f32x4 __attribute__((ext_vector_type(4)));
typedef int   i32x4 __attribute__((ext_vector_type(4)));

// ws layout: [0,1024): int first[256]; [1024, 1024+819200): float posT[200*1024]
#define WS_FIRST_BYTES 1024

// ---------- prep: sinusoid table + first-pad index (identical to R3) ----------
__global__ void prep_kernel(const int* __restrict__ x, int* __restrict__ first,
                            float* __restrict__ posT) {
    const int idx = blockIdx.x * blockDim.x + threadIdx.x;
    if (idx < SS * DD) {
        const int s = idx >> 10;           // /1024
        const int j = idx & (DD - 1);
        const int p = j >> 1;
        const float C = (float)(13.287712379549449 / 512.0);  // log2(10000)/512
        const float angle = (float)s / exp2f((float)p * C);
        posT[idx] = (j & 1) ? cosf(angle) : sinf(angle);
    }
    if (blockIdx.x < BB) {
        __shared__ int sfirst;
        if (threadIdx.x == 0) sfirst = SS - 1;   // no-pad => S-1 (reference semantics)
        __syncthreads();
        if (threadIdx.x < SS && x[blockIdx.x * SS + threadIdx.x] == PAD_ID)
            atomicMin(&sfirst, threadIdx.x);
        __syncthreads();
        if (threadIdx.x == 0) first[blockIdx.x] = sfirst;
    }
}

// ---------- work: R3's static split; out loop unrolled x2 for gather MLP ----------
__global__ void work_kernel(const int* __restrict__ x, const int* __restrict__ first,
                            const float* __restrict__ weight, const float* __restrict__ posT,
                            float* __restrict__ out, float* __restrict__ mask) {
    if (blockIdx.x < MBLK) {
        // mask[b,h,i,j] = (x[b,j]==PAD) || (i>=first[b]) ? 1 : 0 — streaming write
        const int stride = MBLK * 256;
        for (int c = blockIdx.x * 256 + threadIdx.x; c < MASK_CHUNKS; c += stride) {
            const int row = c / 50;              // 50 float4 per S=200 row
            const int j4  = c - row * 50;
            const int b   = row / (HH * SS);     // /3200
            const int i   = row % SS;
            f32x4 v;
            if (i >= first[b]) {
                v = (f32x4){1.f, 1.f, 1.f, 1.f};
            } else {
                const i32x4 xv = ((const i32x4*)x)[b * 50 + j4];   // 204KB, cache-hot
                v.x = (xv.x == PAD_ID) ? 1.f : 0.f;
                v.y = (xv.y == PAD_ID) ? 1.f : 0.f;
                v.z = (xv.z == PAD_ID) ? 1.f : 0.f;
                v.w = (xv.w == PAD_ID) ? 1.f : 0.f;
            }
            __builtin_nontemporal_store(v, (f32x4*)mask + c);
        }
    } else {
        // out[row,:] = weight[x[row],:] + posT[row%S,:]
        // Unrolled x2: two rows per iteration -> 4 independent loads in flight
        // (2 gathers + 2 posT) before any dependent store: 2x gather MLP.
        const int ob = blockIdx.x - MBLK;
        const int OB = NBLK - MBLK;              // 672
        const int t  = threadIdx.x;              // 256 threads x float4 = 1024 floats
        int row = ob;
        for (; row + OB < OUT_ROWS; row += 2 * OB) {
            const int r0 = row, r1 = row + OB;
            const int s0 = r0 % SS,  s1 = r1 % SS;
            const int i0 = x[r0],    i1 = x[r1];     // block-uniform
            const f32x4 w0  = ((const f32x4*)(weight + (size_t)i0 * DD))[t];
            const f32x4 w1  = ((const f32x4*)(weight + (size_t)i1 * DD))[t];
            const f32x4 p0  = ((const f32x4*)(posT + (size_t)s0 * DD))[t];
            const f32x4 p1  = ((const f32x4*)(posT + (size_t)s1 * DD))[t];
            __builtin_nontemporal_store(w0 + p0, (f32x4*)(out + (size_t)r0 * DD) + t);
            __builtin_nontemporal_store(w1 + p1, (f32x4*)(out + (size_t)r1 * DD) + t);
        }
        if (row < OUT_ROWS) {
            const int s   = row % SS;
            const int idx = x[row];
            const f32x4 w  = ((const f32x4*)(weight + (size_t)idx * DD))[t];
            const f32x4 pe = ((const f32x4*)(posT + (size_t)s * DD))[t];
            __builtin_nontemporal_store(w + pe, (f32x4*)(out + (size_t)row * DD) + t);
        }
    }
}

extern "C" void kernel_launch(void* const* d_in, const int* in_sizes, int n_in,
                              void* d_out, int out_size, void* d_ws, size_t ws_size,
                              hipStream_t stream) {
    const int*   x      = (const int*)d_in[0];
    const float* weight = (const float*)d_in[1];
    float* out  = (float*)d_out;
    float* mask = out + (size_t)BB * SS * DD;   // outputs concatenated: (out, mask)

    int*   first = (int*)d_ws;
    float* posT  = (float*)((char*)d_ws + WS_FIRST_BYTES);

    prep_kernel<<<(SS * DD + 255) / 256, 256, 0, stream>>>(x, first, posT);
    work_kernel<<<NBLK, 256, 0, stream>>>(x, first, weight, posT, out, mask);
}